// Round 6
// baseline (439.930 us; speedup 1.0000x reference)
//
#include <hip/hip_runtime.h>

// WaveRNN: damped 2D wave equation, B=16, T=256, 256x256 grid, 3 probes.
// 8 slabs per batch (128 WGs x 512 threads, cooperative). Wave w owns rows
// s*32+4w..+3; lane l owns cols 4l..4l+3 (4x4 register tile).
// NO __syncthreads in the main loop.
//   intra-WG : barrier-free tagged LDS rows (vals -> lgkmcnt(0) -> tag;
//              in-order DS drain => tag-visible implies vals-visible).
//              Substep order: interior rows first, poll late, publish early.
//   inter-WG : K=4 temporal blocking. Boundary waves keep 4 ghost rows (both
//              time levels) in registers and step them redundantly
//              (shrinking trapezoid), so the global exchange (tagged 8-byte
//              {chunk,value} packets, relaxed agent-scope, parity
//              double-buffered, coalesced layout) runs once per 4 steps.
// Skew between neighbors is bounded to 1 substep (1 chunk globally) by the
// mutual data dependency; the same induction proves the parity slot being
// overwritten was already consumed. No fences, no deadlock.

#define B_    16
#define T_    256
#define NY    256
#define NP    3
#define NSLAB 8
#define WAVES 8
#define THREADS 512
#define NIF   (NSLAB - 1)
#define KCH   4
#define NCHUNK (T_ / KCH)

// chunk exchange: [batch][iface][side][parity][rowfield 0..7][packed col]
// side0: slab i's bottom 4 owned rows  -> slab i+1's up ghosts
// side1: slab i+1's top 4 owned rows   -> slab i's dn ghosts
// rowfield 0..3 = h1 rows, 4..7 = h2 rows; packed col = j*64 + lane
__device__ uint64_t g_halo[B_][NIF][2][2][8][NY];

__global__ void reset_halo()
{
    const int n = B_ * NIF * 2 * 2 * 8 * NY;
    int i = blockIdx.x * blockDim.x + threadIdx.x;
    if (i < n) (&g_halo[0][0][0][0][0][0])[i] = 0ull;
}

#define PACK(tag, f) (((uint64_t)(uint32_t)(tag) << 32) | (uint64_t)__float_as_uint(f))

// hn = h2 + TC*(h1-h2) + CC*(s4 - 4*h1), written into H2[r] in place.
#define ROWC(H1, H2, r, UPA, DNA) do { \
    float lf_ = __shfl_up(H1[r][3], 1, 64); \
    float rt_ = __shfl_down(H1[r][0], 1, 64); \
    if (l == 0)  lf_ = 0.f; \
    if (l == 63) rt_ = 0.f; \
    _Pragma("unroll") for (int j = 0; j < 4; ++j) { \
        const float lv_ = (j == 0) ? lf_ : H1[r][j - 1]; \
        const float rv_ = (j == 3) ? rt_ : H1[r][j + 1]; \
        const float s4_ = (UPA[j] + DNA[j]) + (lv_ + rv_); \
        const float d_  = H1[r][j] - H2[r][j]; \
        const float e_  = fmaf(-4.0f, H1[r][j], s4_); \
        float v_ = fmaf(CC[r][j], e_, H2[r][j]); \
        v_ = fmaf(TC[r][j], d_, v_); \
        H2[r][j] = v_; \
    } \
} while (0)

#define SRCP(H2, r, TT) do { \
    if (srcHere && src_r == (r)) { \
        _Pragma("unroll") for (int j = 0; j < 4; ++j) \
            if (src_c == j) H2[r][j] += xbuf[TT]; \
    } \
    _Pragma("unroll") for (int qq = 0; qq < NP; ++qq) { \
        if (pHere[qq] && pr[qq] == (r)) { \
            float v_ = 0.f; \
            _Pragma("unroll") for (int j = 0; j < 4; ++j) \
                if (pc[qq] == j) v_ = H2[r][j]; \
            out[((size_t)b * T_ + (TT)) * NP + qq] = v_; \
        } \
    } \
} while (0)

// ghost trapezoid (boundary waves): update still-valid ghost rows t -> t+1.
// upG: ghost rows are r0-4..r0-1 (GA idx 0..3); valid updates i >= K_+1.
// dnG: ghost rows are r0+4..r0+7 (GA idx 0..3); valid updates i <= 2-K_.
#define GHOSTS(H1, GA, GB, K_, TT) do { \
    if (upG) { \
        _Pragma("unroll") for (int i = 1; i < 4; ++i) { \
            if (i >= (K_) + 1) { \
                float lf_ = __shfl_up(GA[i][3], 1, 64); \
                float rt_ = __shfl_down(GA[i][0], 1, 64); \
                if (l == 0)  lf_ = 0.f; \
                if (l == 63) rt_ = 0.f; \
                _Pragma("unroll") for (int j = 0; j < 4; ++j) { \
                    const float lv_ = (j == 0) ? lf_ : GA[i][j - 1]; \
                    const float rv_ = (j == 3) ? rt_ : GA[i][j + 1]; \
                    const float av_ = GA[i - 1][j]; \
                    const float dv_ = (i == 3) ? H1[0][j] : GA[i + 1][j]; \
                    const float s4_ = (av_ + dv_) + (lv_ + rv_); \
                    const float d_  = GA[i][j] - GB[i][j]; \
                    const float e_  = fmaf(-4.0f, GA[i][j], s4_); \
                    float v_ = fmaf(gCC[i][j], e_, GB[i][j]); \
                    v_ = fmaf(gTC[i][j], d_, v_); \
                    if (gsrcHere && i == gsrc_r && j == gsrc_c) v_ += xbuf[TT]; \
                    GB[i][j] = v_; \
                } \
            } \
        } \
    } \
    if (dnG) { \
        _Pragma("unroll") for (int i = 0; i < 3; ++i) { \
            if (i <= 2 - (K_)) { \
                float lf_ = __shfl_up(GA[i][3], 1, 64); \
                float rt_ = __shfl_down(GA[i][0], 1, 64); \
                if (l == 0)  lf_ = 0.f; \
                if (l == 63) rt_ = 0.f; \
                _Pragma("unroll") for (int j = 0; j < 4; ++j) { \
                    const float lv_ = (j == 0) ? lf_ : GA[i][j - 1]; \
                    const float rv_ = (j == 3) ? rt_ : GA[i][j + 1]; \
                    const float av_ = (i == 0) ? H1[3][j] : GA[i - 1][j]; \
                    const float dv_ = GA[i + 1][j]; \
                    const float s4_ = (av_ + dv_) + (lv_ + rv_); \
                    const float d_  = GA[i][j] - GB[i][j]; \
                    const float e_  = fmaf(-4.0f, GA[i][j], s4_); \
                    float v_ = fmaf(gCC[i][j], e_, GB[i][j]); \
                    v_ = fmaf(gTC[i][j], d_, v_); \
                    if (gsrcHere && i == gsrc_r && j == gsrc_c) v_ += xbuf[TT]; \
                    GB[i][j] = v_; \
                } \
            } \
        } \
    } \
} while (0)

// One substep: H1=h^t, H2=h^{t-1} -> h^{t+1} into H2. K_ = substep in chunk.
// Order: interior rows -> acquire neighbors (late) -> boundary rows ->
// publish (early) -> ghost trapezoid -> interior src/probes.
#define SUB(H1, H2, GA, GB, K_, TT) do { \
    const int P_ = (K_) & 1; \
    const int Q_ = ((K_) + 1) & 1; \
    ROWC(H1, H2, 1, H1[0], H1[2]); \
    ROWC(H1, H2, 2, H1[1], H1[3]); \
    float gu_[4], gd_[4]; \
    if (w == 0) { \
        if (s == 0) { gu_[0] = gu_[1] = gu_[2] = gu_[3] = 0.f; } \
        else { gu_[0] = GA[3][0]; gu_[1] = GA[3][1]; gu_[2] = GA[3][2]; gu_[3] = GA[3][3]; } \
    } else { \
        while (__hip_atomic_load(&r3t[w - 1][P_], __ATOMIC_RELAXED, __HIP_MEMORY_SCOPE_WORKGROUP) != (TT)) {} \
        asm volatile("" ::: "memory"); \
        const float4 u4_ = *reinterpret_cast<const float4*>(&r3v[w - 1][P_][y0]); \
        gu_[0] = u4_.x; gu_[1] = u4_.y; gu_[2] = u4_.z; gu_[3] = u4_.w; \
    } \
    if (w == WAVES - 1) { \
        if (s == NSLAB - 1) { gd_[0] = gd_[1] = gd_[2] = gd_[3] = 0.f; } \
        else { gd_[0] = GA[0][0]; gd_[1] = GA[0][1]; gd_[2] = GA[0][2]; gd_[3] = GA[0][3]; } \
    } else { \
        while (__hip_atomic_load(&r0t[w + 1][P_], __ATOMIC_RELAXED, __HIP_MEMORY_SCOPE_WORKGROUP) != (TT)) {} \
        asm volatile("" ::: "memory"); \
        const float4 d4_ = *reinterpret_cast<const float4*>(&r0v[w + 1][P_][y0]); \
        gd_[0] = d4_.x; gd_[1] = d4_.y; gd_[2] = d4_.z; gd_[3] = d4_.w; \
    } \
    ROWC(H1, H2, 0, gu_, H1[1]); \
    ROWC(H1, H2, 3, H1[2], gd_); \
    SRCP(H2, 0, TT); \
    SRCP(H2, 3, TT); \
    if (w > 0) \
        *reinterpret_cast<float4*>(&r0v[w][Q_][y0]) = make_float4(H2[0][0], H2[0][1], H2[0][2], H2[0][3]); \
    if (w < WAVES - 1) \
        *reinterpret_cast<float4*>(&r3v[w][Q_][y0]) = make_float4(H2[3][0], H2[3][1], H2[3][2], H2[3][3]); \
    asm volatile("s_waitcnt lgkmcnt(0)" ::: "memory"); \
    if (l == 0) { \
        if (w > 0) \
            __hip_atomic_store(&r0t[w][Q_], (TT) + 1, __ATOMIC_RELAXED, __HIP_MEMORY_SCOPE_WORKGROUP); \
        if (w < WAVES - 1) \
            __hip_atomic_store(&r3t[w][Q_], (TT) + 1, __ATOMIC_RELAXED, __HIP_MEMORY_SCOPE_WORKGROUP); \
    } \
    GHOSTS(H1, GA, GB, K_, TT); \
    SRCP(H2, 1, TT); \
    SRCP(H2, 2, TT); \
} while (0)

__launch_bounds__(THREADS, 2)
__global__ void wave_multi(const float* __restrict__ xin,
                           const float* __restrict__ cin,
                           const float* __restrict__ bin,
                           const int* __restrict__ pxp,
                           const int* __restrict__ pyp,
                           const int* __restrict__ sxp,
                           const int* __restrict__ syp,
                           float* __restrict__ out)
{
    const int blk = blockIdx.x;
    const int b = blk >> 3;           // batch
    const int s = blk & 7;            // slab: rows [s*32, s*32+32)
    const int tid = threadIdx.x;
    const int w = tid >> 6;           // wave 0..7
    const int l = tid & 63;           // lane
    const int r0 = s * 32 + w * 4;    // global row of tile row 0
    const int y0 = l * 4;             // global col of tile col 0

    __shared__ float xbuf[T_];
    __shared__ float r0v[WAVES][2][NY];   // wave w's row0 values, by parity
    __shared__ float r3v[WAVES][2][NY];   // wave w's row3 values, by parity
    __shared__ int   r0t[WAVES][2];       // tags
    __shared__ int   r3t[WAVES][2];

    for (int i = tid; i < WAVES * 2 * NY; i += THREADS) {
        (&r0v[0][0][0])[i] = 0.f;
        (&r3v[0][0][0])[i] = 0.f;
    }
    if (tid < WAVES * 2) {
        const int w_ = tid >> 1, p_ = tid & 1;
        r0t[w_][p_] = (p_ == 0) ? 0 : -1;   // parity0 holds valid step-0 zeros
        r3t[w_][p_] = (p_ == 0) ? 0 : -1;
    }
    if (tid < T_) xbuf[tid] = xin[b * T_ + tid];

    // owned state + compressed coefficients: TC = 2*c1, CC = c1*(DT^2*c^2)
    // hn = h2 + TC*(h1-h2) + CC*(s4 - 4*h1)   [c1*c2 == 2*c1 - 1]
    float h1[4][4], h2[4][4], TC[4][4], CC[4][4];
#pragma unroll
    for (int r = 0; r < 4; ++r) {
        const float4 cv = *reinterpret_cast<const float4*>(&cin[(r0 + r) * NY + y0]);
        const float4 bv = *reinterpret_cast<const float4*>(&bin[(r0 + r) * NY + y0]);
        const float cvv[4] = {cv.x, cv.y, cv.z, cv.w};
        const float bvv[4] = {bv.x, bv.y, bv.z, bv.w};
#pragma unroll
        for (int j = 0; j < 4; ++j) {
            const float c1  = 1.0f / (1.0f + 0.25f * bvv[j]);
            const float csq = 0.25f * cvv[j] * cvv[j];
            TC[r][j] = 2.0f * c1;
            CC[r][j] = c1 * csq;
            h1[r][j] = 0.f;
            h2[r][j] = 0.f;
        }
    }

    // register ghosts for slab-boundary waves
    const bool upG = (w == 0 && s > 0);
    const bool dnG = (w == WAVES - 1 && s < NSLAB - 1);
    const int gr0 = upG ? (r0 - 4) : (dnG ? (r0 + 4) : r0);
    float ga[4][4], gb[4][4], gTC[4][4], gCC[4][4];
#pragma unroll
    for (int i = 0; i < 4; ++i) {
        const float4 cv = *reinterpret_cast<const float4*>(&cin[(gr0 + i) * NY + y0]);
        const float4 bv = *reinterpret_cast<const float4*>(&bin[(gr0 + i) * NY + y0]);
        const float cvv[4] = {cv.x, cv.y, cv.z, cv.w};
        const float bvv[4] = {bv.x, bv.y, bv.z, bv.w};
#pragma unroll
        for (int j = 0; j < 4; ++j) {
            const float c1  = 1.0f / (1.0f + 0.25f * bvv[j]);
            const float csq = 0.25f * cvv[j] * cvv[j];
            gTC[i][j] = 2.0f * c1;
            gCC[i][j] = c1 * csq;
            ga[i][j] = 0.f;
            gb[i][j] = 0.f;
        }
    }

    const int sx = sxp[0], sy = syp[0];
    const bool srcHere = (sx >= r0 && sx < r0 + 4 && sy >= y0 && sy < y0 + 4);
    const int  src_r = sx - r0, src_c = sy - y0;
    const bool gsrcHere = (upG || dnG) && (sx >= gr0 && sx < gr0 + 4 && sy >= y0 && sy < y0 + 4);
    const int  gsrc_r = sx - gr0, gsrc_c = sy - y0;
    bool pHere[NP];
    int  pr[NP], pc[NP];
#pragma unroll
    for (int q = 0; q < NP; ++q) {
        const int pxx = pxp[q], pyy = pyp[q];
        pHere[q] = (pxx >= r0 && pxx < r0 + 4 && pyy >= y0 && pyy < y0 + 4);
        pr[q] = pxx - r0;
        pc[q] = pyy - y0;
    }

    __syncthreads();   // the only barrier: LDS init

#pragma unroll 1
    for (int c = 0; c < NCHUNK; ++c) {
        // receive ghosts for this chunk: neighbor rows at h^{4c}, h^{4c-1}
        if ((c > 0) && (upG || dnG)) {
            const int iface = upG ? (s - 1) : s;
            const int side  = upG ? 0 : 1;
            uint64_t* gp = &g_halo[b][iface][side][c & 1][0][0];
            uint64_t vv[8][4];
            bool ok;
            do {
                ok = true;
#pragma unroll
                for (int rf = 0; rf < 8; ++rf)
#pragma unroll
                    for (int j = 0; j < 4; ++j)
                        vv[rf][j] = __hip_atomic_load(gp + rf * NY + j * 64 + l,
                                                      __ATOMIC_RELAXED, __HIP_MEMORY_SCOPE_AGENT);
#pragma unroll
                for (int rf = 0; rf < 8; ++rf)
#pragma unroll
                    for (int j = 0; j < 4; ++j)
                        ok = ok && ((uint32_t)(vv[rf][j] >> 32) == (uint32_t)c);
            } while (!ok);
#pragma unroll
            for (int i = 0; i < 4; ++i)
#pragma unroll
                for (int j = 0; j < 4; ++j) {
                    ga[i][j] = __uint_as_float((uint32_t)vv[i][j]);
                    gb[i][j] = __uint_as_float((uint32_t)vv[4 + i][j]);
                }
        }

        SUB(h1, h2, ga, gb, 0, 4 * c + 0);
        SUB(h2, h1, gb, ga, 1, 4 * c + 1);
        SUB(h1, h2, ga, gb, 2, 4 * c + 2);
        SUB(h2, h1, gb, ga, 3, 4 * c + 3);
        // now h1 = h^{4c+4}, h2 = h^{4c+3}

        // publish owned rows (both levels) for neighbors' next chunk
        if ((c + 1 < NCHUNK) && (upG || dnG)) {
            const int iface = upG ? (s - 1) : s;
            const int side  = upG ? 1 : 0;
            uint64_t* gp = &g_halo[b][iface][side][(c + 1) & 1][0][0];
#pragma unroll
            for (int i = 0; i < 4; ++i)
#pragma unroll
                for (int j = 0; j < 4; ++j) {
                    __hip_atomic_store(gp + i * NY + j * 64 + l, PACK(c + 1, h1[i][j]),
                                       __ATOMIC_RELAXED, __HIP_MEMORY_SCOPE_AGENT);
                    __hip_atomic_store(gp + (4 + i) * NY + j * 64 + l, PACK(c + 1, h2[i][j]),
                                       __ATOMIC_RELAXED, __HIP_MEMORY_SCOPE_AGENT);
                }
        }
    }
}

extern "C" void kernel_launch(void* const* d_in, const int* in_sizes, int n_in,
                              void* d_out, int out_size, void* d_ws, size_t ws_size,
                              hipStream_t stream)
{
    const float* x  = (const float*)d_in[0];
    const float* c  = (const float*)d_in[1];
    const float* bb = (const float*)d_in[2];
    const int*   px = (const int*)d_in[3];
    const int*   py = (const int*)d_in[4];
    const int*   sx = (const int*)d_in[5];
    const int*   sy = (const int*)d_in[6];
    float* out = (float*)d_out;

    const int words = B_ * NIF * 2 * 2 * 8 * NY;
    reset_halo<<<(words + 255) / 256, 256, 0, stream>>>();

    void* args[] = { (void*)&x, (void*)&c, (void*)&bb, (void*)&px, (void*)&py,
                     (void*)&sx, (void*)&sy, (void*)&out };
    hipLaunchCooperativeKernel(reinterpret_cast<void*>(wave_multi),
                               dim3(B_ * NSLAB), dim3(THREADS), args, 0, stream);
}